// Round 1
// baseline (4796.445 us; speedup 1.0000x reference)
//
#include <hip/hip_runtime.h>
#include <cstdint>
#include <cstddef>

__device__ __forceinline__ float elu_f(float x) { return x > 0.f ? x : expm1f(x); }

// ---------------- edge MLP: h_l = relu(edge_attr @ w1_l + b1_l) ----------------
__global__ __launch_bounds__(256)
void edge_mlp_kernel(const float* __restrict__ ea,
                     const float* __restrict__ w1a, const float* __restrict__ b1a, float* __restrict__ h1,
                     const float* __restrict__ w1b, const float* __restrict__ b1b, float* __restrict__ h2,
                     const float* __restrict__ w1c, const float* __restrict__ b1c, float* __restrict__ h3)
{
    const int e   = blockIdx.x;
    const int tid = threadIdx.x;
    __shared__ float a[5];
    if (tid < 5) a[tid] = ea[e * 5 + tid];
    __syncthreads();
    // h1: 512 wide
    #pragma unroll
    for (int cc = 0; cc < 2; ++cc) {
        int c = tid + cc * 256;
        float s = b1a[c];
        #pragma unroll
        for (int j = 0; j < 5; ++j) s = fmaf(a[j], w1a[j * 512 + c], s);
        h1[(size_t)e * 512 + c] = fmaxf(s, 0.f);
    }
    // h2, h3: 128 wide
    if (tid < 128) {
        float s = b1b[tid];
        float t = b1c[tid];
        #pragma unroll
        for (int j = 0; j < 5; ++j) {
            s = fmaf(a[j], w1b[j * 128 + tid], s);
            t = fmaf(a[j], w1c[j * 128 + tid], t);
        }
        h2[(size_t)e * 128 + tid] = fmaxf(s, 0.f);
        h3[(size_t)e * 128 + tid] = fmaxf(t, 0.f);
    }
}

// ---------------- fused message/node GEMM ----------------
// MODE 0 (message): out_agg[dst[e]][o] += sum_{k,i} h[e][k]*xin[src[e]][i]*w2[(k*CIN+i)*COUT+o]
//                                        + sum_i xin[src[e]][i]*bslab[i*COUT+o]      (bslab = b2)
// MODE 1 (node):    out[n][o] = elu( sum_i xin[n][i]*bslab[i*COUT+o] + agg_in[n][o] + bias[o] )
//                   (bslab = root; KH must be 0)
template <int KH, int CIN, int COUT, int MODE>
__global__ __launch_bounds__(256)
void fused_gemm_kernel(const float* __restrict__ xin,
                       const float* __restrict__ h,
                       const float* __restrict__ w2,
                       const float* __restrict__ bslab,
                       const int* __restrict__ src,
                       const int* __restrict__ dst,
                       const float* __restrict__ agg_in,
                       const float* __restrict__ bias,
                       float* __restrict__ out)
{
    constexpr int BM  = 64;
    constexpr int BN  = 64;
    constexpr int BKI = (CIN % 32 == 0) ? 32 : 16;
    constexpr int CIN_PAD = ((CIN + BKI - 1) / BKI) * BKI;
    constexpr int CPK = CIN_PAD / BKI;           // chunks per k-slab
    constexpr int NROWS = BKI / 16;              // B-tile rows loaded per thread

    __shared__ __align__(16) float xs_t[CIN_PAD][BM];   // transposed gathered inputs
    __shared__ __align__(16) float btile[BKI][BN];
    __shared__ int s_src[BM];

    const int tid = threadIdx.x;
    const int tx  = tid & 15;      // n-group
    const int ty  = tid >> 4;      // m-group
    const int ty4 = ty * 4;
    const int tx4 = tx * 4;
    const int e0  = blockIdx.x * BM;
    const int n0  = blockIdx.y * BN;

    if (MODE == 0) { if (tid < BM) s_src[tid] = src[e0 + tid]; }
    __syncthreads();

    // stage transposed input tile (zero-padded rows above CIN)
    for (int idx = tid; idx < BM * CIN_PAD; idx += 256) {
        int m = idx / CIN_PAD;
        int i = idx - m * CIN_PAD;
        int row = (MODE == 0) ? s_src[m] : (e0 + m);
        float v = 0.f;
        if (i < CIN) v = xin[(size_t)row * CIN + i];
        xs_t[i][m] = v;
    }

    const int total_chunks = (KH + 1) * CPK;
    const int rbase = tid >> 4;          // 0..15
    const int nn    = (tid & 15) * 4;

    float acc[4][4] = {};
    float4 pre[NROWS];

    // prefetch chunk 0
    {
        int k  = 0, i0 = 0;
        const float* brow = (0 < KH) ? (w2 + (size_t)((size_t)k * CIN + i0) * COUT + n0)
                                     : (bslab + (size_t)i0 * COUT + n0);
        #pragma unroll
        for (int rr = 0; rr < NROWS; ++rr) {
            int r = rbase + rr * 16;
            float4 v = {0.f, 0.f, 0.f, 0.f};
            if (i0 + r < CIN) v = *(const float4*)(brow + (size_t)r * COUT + nn);
            pre[rr] = v;
        }
    }

    for (int c = 0; c < total_chunks; ++c) {
        __syncthreads();
        #pragma unroll
        for (int rr = 0; rr < NROWS; ++rr)
            *(float4*)&btile[rbase + rr * 16][nn] = pre[rr];
        __syncthreads();

        // prefetch next chunk into registers (hidden under compute)
        if (c + 1 < total_chunks) {
            int cn = c + 1;
            int kn = cn / CPK;
            int i0n = (cn - kn * CPK) * BKI;
            const float* brow = (kn < KH) ? (w2 + (size_t)((size_t)kn * CIN + i0n) * COUT + n0)
                                          : (bslab + (size_t)i0n * COUT + n0);
            #pragma unroll
            for (int rr = 0; rr < NROWS; ++rr) {
                int r = rbase + rr * 16;
                float4 v = {0.f, 0.f, 0.f, 0.f};
                if (i0n + r < CIN) v = *(const float4*)(brow + (size_t)r * COUT + nn);
                pre[rr] = v;
            }
        }

        const int k  = c / CPK;
        const int i0 = (c - k * CPK) * BKI;

        float ha[4];
        if (MODE == 0 && k < KH) {
            const float* hp = h + (size_t)(e0 + ty4) * KH + k;
            ha[0] = hp[0]; ha[1] = hp[KH]; ha[2] = hp[2 * (size_t)KH]; ha[3] = hp[3 * (size_t)KH];
        } else {
            ha[0] = ha[1] = ha[2] = ha[3] = 1.f;
        }

        #pragma unroll
        for (int ii = 0; ii < BKI; ++ii) {
            float4 xv = *(const float4*)&xs_t[i0 + ii][ty4];
            float4 bv = *(const float4*)&btile[ii][tx4];
            float av[4];
            av[0] = ha[0] * xv.x; av[1] = ha[1] * xv.y;
            av[2] = ha[2] * xv.z; av[3] = ha[3] * xv.w;
            float bvv[4] = {bv.x, bv.y, bv.z, bv.w};
            #pragma unroll
            for (int m = 0; m < 4; ++m)
                #pragma unroll
                for (int n = 0; n < 4; ++n)
                    acc[m][n] = fmaf(av[m], bvv[n], acc[m][n]);
        }
    }

    if (MODE == 0) {
        #pragma unroll
        for (int m = 0; m < 4; ++m) {
            int d = dst[e0 + ty4 + m];
            float* p = out + (size_t)d * COUT + n0 + tx4;
            atomicAdd(p + 0, acc[m][0]);
            atomicAdd(p + 1, acc[m][1]);
            atomicAdd(p + 2, acc[m][2]);
            atomicAdd(p + 3, acc[m][3]);
        }
    } else {
        float bs[4];
        #pragma unroll
        for (int n = 0; n < 4; ++n) bs[n] = bias[n0 + tx4 + n];
        #pragma unroll
        for (int m = 0; m < 4; ++m) {
            size_t base = (size_t)(e0 + ty4 + m) * COUT + n0 + tx4;
            #pragma unroll
            for (int n = 0; n < 4; ++n) {
                float v = acc[m][n] + agg_in[base + n] + bs[n];
                out[base + n] = elu_f(v);
            }
        }
    }
}

// ---------------- graph pooling: segment sum + count ----------------
__global__ __launch_bounds__(256)
void seg_sum_kernel(const float* __restrict__ hl3, const int* __restrict__ batch,
                    float* __restrict__ gsum, float* __restrict__ gcnt)
{
    const int n = blockIdx.x;
    const int b = batch[n];
    const int o = threadIdx.x;
    atomicAdd(&gsum[(size_t)b * 256 + o], hl3[(size_t)n * 256 + o]);
    if (o == 0) atomicAdd(&gcnt[b], 1.f);
}

// ---------------- readout MLP: 256 -> 128 -> 64 -> 1 ----------------
__global__ __launch_bounds__(256)
void readout_kernel(const float* __restrict__ gsum, const float* __restrict__ gcnt,
                    const float* __restrict__ fc1w, const float* __restrict__ fc1b,
                    const float* __restrict__ fc2w, const float* __restrict__ fc2b,
                    const float* __restrict__ fc3w, const float* __restrict__ fc3b,
                    float* __restrict__ outp)
{
    const int g   = blockIdx.x;
    const int tid = threadIdx.x;
    __shared__ float gm[256];
    __shared__ float a1[128];
    __shared__ float a2[64];
    float cnt = fmaxf(gcnt[g], 1.f);
    gm[tid] = gsum[(size_t)g * 256 + tid] / cnt;
    __syncthreads();
    if (tid < 128) {
        float s = fc1b[tid];
        for (int j = 0; j < 256; ++j) s = fmaf(gm[j], fc1w[j * 128 + tid], s);
        a1[tid] = elu_f(s);
    }
    __syncthreads();
    if (tid < 64) {
        float s = fc2b[tid];
        for (int j = 0; j < 128; ++j) s = fmaf(a1[j], fc2w[j * 64 + tid], s);
        a2[tid] = elu_f(s);
    }
    __syncthreads();
    if (tid == 0) {
        float s = fc3b[0];
        for (int j = 0; j < 64; ++j) s = fmaf(a2[j], fc3w[j], s);
        outp[g] = s;
    }
}

extern "C" void kernel_launch(void* const* d_in, const int* in_sizes, int n_in,
                              void* d_out, int out_size, void* d_ws, size_t ws_size,
                              hipStream_t stream)
{
    const float* x      = (const float*)d_in[0];
    const int*   ei     = (const int*)  d_in[1];
    const float* ea     = (const float*)d_in[2];
    const int*   batch  = (const int*)  d_in[3];
    const float* nn1_w1 = (const float*)d_in[4];
    const float* nn1_b1 = (const float*)d_in[5];
    const float* nn1_w2 = (const float*)d_in[6];
    const float* nn1_b2 = (const float*)d_in[7];
    const float* root1  = (const float*)d_in[8];
    const float* bias1  = (const float*)d_in[9];
    const float* nn2_w1 = (const float*)d_in[10];
    const float* nn2_b1 = (const float*)d_in[11];
    const float* nn2_w2 = (const float*)d_in[12];
    const float* nn2_b2 = (const float*)d_in[13];
    const float* root2  = (const float*)d_in[14];
    const float* bias2  = (const float*)d_in[15];
    const float* nn3_w1 = (const float*)d_in[16];
    const float* nn3_b1 = (const float*)d_in[17];
    const float* nn3_w2 = (const float*)d_in[18];
    const float* nn3_b2 = (const float*)d_in[19];
    const float* root3  = (const float*)d_in[20];
    const float* bias3  = (const float*)d_in[21];
    const float* fc1_w  = (const float*)d_in[22];
    const float* fc1_b  = (const float*)d_in[23];
    const float* fc2_w  = (const float*)d_in[24];
    const float* fc2_b  = (const float*)d_in[25];
    const float* fc3_w  = (const float*)d_in[26];
    const float* fc3_b  = (const float*)d_in[27];

    const int E = in_sizes[2] / 5;    // 4096
    const int N = in_sizes[0] / 37;   // 4096
    const int* srcp = ei;
    const int* dstp = ei + E;

    float* ws  = (float*)d_ws;
    float* h1   = ws;                              // [E,512]
    float* h2   = h1  + (size_t)E * 512;           // [E,128]
    float* h3   = h2  + (size_t)E * 128;           // [E,128]
    float* hl1  = h3  + (size_t)E * 128;           // [N,128]
    float* hl2  = hl1 + (size_t)N * 128;           // [N,256]
    float* hl3  = hl2 + (size_t)N * 256;           // [N,256]
    float* agg1 = hl3 + (size_t)N * 256;           // [N,128]  -- zeroed region starts here
    float* agg2 = agg1 + (size_t)N * 128;          // [N,256]
    float* agg3 = agg2 + (size_t)N * 256;          // [N,256]
    float* gsum = agg3 + (size_t)N * 256;          // [128,256]
    float* gcnt = gsum + (size_t)128 * 256;        // [128]

    const size_t zero_floats = (size_t)N * 128 + (size_t)N * 256 + (size_t)N * 256
                             + (size_t)128 * 256 + 128;
    hipMemsetAsync(agg1, 0, zero_floats * sizeof(float), stream);

    edge_mlp_kernel<<<E, 256, 0, stream>>>(ea, nn1_w1, nn1_b1, h1,
                                           nn2_w1, nn2_b1, h2,
                                           nn3_w1, nn3_b1, h3);

    const int gm_e = E / 64;   // 64
    const int gm_n = N / 64;   // 64

    // layer 1: cin=37 -> cout=128, edge hidden 512
    fused_gemm_kernel<512, 37, 128, 0><<<dim3(gm_e, 2), 256, 0, stream>>>(
        x, h1, nn1_w2, nn1_b2, srcp, dstp, nullptr, nullptr, agg1);
    fused_gemm_kernel<0, 37, 128, 1><<<dim3(gm_n, 2), 256, 0, stream>>>(
        x, nullptr, nullptr, root1, nullptr, nullptr, agg1, bias1, hl1);

    // layer 2: cin=128 -> cout=256, edge hidden 128
    fused_gemm_kernel<128, 128, 256, 0><<<dim3(gm_e, 4), 256, 0, stream>>>(
        hl1, h2, nn2_w2, nn2_b2, srcp, dstp, nullptr, nullptr, agg2);
    fused_gemm_kernel<0, 128, 256, 1><<<dim3(gm_n, 4), 256, 0, stream>>>(
        hl1, nullptr, nullptr, root2, nullptr, nullptr, agg2, bias2, hl2);

    // layer 3: cin=256 -> cout=256, edge hidden 128
    fused_gemm_kernel<128, 256, 256, 0><<<dim3(gm_e, 4), 256, 0, stream>>>(
        hl2, h3, nn3_w2, nn3_b2, srcp, dstp, nullptr, nullptr, agg3);
    fused_gemm_kernel<0, 256, 256, 1><<<dim3(gm_n, 4), 256, 0, stream>>>(
        hl2, nullptr, nullptr, root3, nullptr, nullptr, agg3, bias3, hl3);

    seg_sum_kernel<<<N, 256, 0, stream>>>(hl3, batch, gsum, gcnt);
    readout_kernel<<<128, 256, 0, stream>>>(gsum, gcnt, fc1_w, fc1_b,
                                            fc2_w, fc2_b, fc3_w, fc3_b,
                                            (float*)d_out);
}

// Round 2
// 664.992 us; speedup vs baseline: 7.2128x; 7.2128x over previous
//
#include <hip/hip_runtime.h>
#include <cstdint>
#include <cstddef>

typedef float f32x4 __attribute__((ext_vector_type(4)));
typedef short s16x8 __attribute__((ext_vector_type(8)));

__device__ __forceinline__ float elu_f(float x) { return x > 0.f ? x : expm1f(x); }

__device__ __forceinline__ unsigned short f2bf(float f) {
    unsigned u = __float_as_uint(f);
    unsigned r = (u + 0x7FFFu + ((u >> 16) & 1u)) >> 16;
    return (unsigned short)r;
}
__device__ __forceinline__ float bf2f(unsigned short b) {
    return __uint_as_float(((unsigned)b) << 16);
}

// ---------------- edge MLP: hT_l[c][e] = relu(edge_attr @ w1_l + b1_l) (transposed) ----
__global__ __launch_bounds__(256)
void edge_mlp_kernel(const float* __restrict__ ea,
                     const float* __restrict__ w1a, const float* __restrict__ b1a, float* __restrict__ h1T,
                     const float* __restrict__ w1b, const float* __restrict__ b1b, float* __restrict__ h2T,
                     const float* __restrict__ w1c, const float* __restrict__ b1c, float* __restrict__ h3T,
                     int E)
{
    const int e   = blockIdx.x;
    const int tid = threadIdx.x;
    __shared__ float a[5];
    if (tid < 5) a[tid] = ea[e * 5 + tid];
    __syncthreads();
    #pragma unroll
    for (int cc = 0; cc < 2; ++cc) {
        int c = tid + cc * 256;
        float s = b1a[c];
        #pragma unroll
        for (int j = 0; j < 5; ++j) s = fmaf(a[j], w1a[j * 512 + c], s);
        h1T[(size_t)c * E + e] = fmaxf(s, 0.f);
    }
    if (tid < 128) {
        float s = b1b[tid];
        float t = b1c[tid];
        #pragma unroll
        for (int j = 0; j < 5; ++j) {
            s = fmaf(a[j], w1b[j * 128 + tid], s);
            t = fmaf(a[j], w1c[j * 128 + tid], t);
        }
        h2T[(size_t)tid * E + e] = fmaxf(s, 0.f);
        h3T[(size_t)tid * E + e] = fmaxf(t, 0.f);
    }
}

// ---------------- MFMA message kernel ----------------
// agg[dst[e]][n0+n] += sum_{kh in block range} h[e,kh] * (X @ W2[kh])[e,n] (+ X @ b2 at kh==KH)
// X rows gathered via src[], held in registers as bf16 hi/lo fragments.
// 3-product split precision: AhBh + AhBl + AlBh (fp32 accumulate).
template <int KH, int CIN, int COUT>
__global__ __launch_bounds__(256, 2)
void msg_mfma_kernel(const float* __restrict__ xin,   // [N, CIN]
                     const float* __restrict__ hT,    // [KH, E]
                     const float* __restrict__ w2,    // [KH*CIN, COUT]
                     const float* __restrict__ b2,    // [CIN*COUT]
                     const int* __restrict__ src,
                     const int* __restrict__ dst,
                     float* __restrict__ agg,         // [N, COUT]
                     int E, int khg_per)
{
    constexpr int BM = 128;
    constexpr int BN = 64;
    constexpr int KF = (CIN + 31) / 32;      // 32-k chunks per kh slab
    constexpr int PITCH = 48;                // shorts per B row (96B: 16B-aligned frag reads)

    __shared__ short bsh[2][2][BN][PITCH];   // [buf][hi/lo][n][k]
    __shared__ float s_h[2][BM];
    __shared__ int   s_src[BM];
    __shared__ int   s_dst[BM];

    const int tid  = threadIdx.x;
    const int lane = tid & 63;
    const int w    = tid >> 6;        // wave 0..3 -> rows w*32..w*32+31
    const int l15  = lane & 15;
    const int lg   = lane >> 4;       // 0..3
    const int e0   = blockIdx.x * BM;
    const int n0   = blockIdx.y * BN;
    const int kh0  = blockIdx.z * khg_per;
    const int kh1  = min(kh0 + khg_per, KH + 1);

    if (tid < BM) { s_src[tid] = src[e0 + tid]; s_dst[tid] = dst[e0 + tid]; }
    __syncthreads();

    // ---- gather A (X rows) into register fragments, hi/lo bf16 ----
    s16x8 a_hi[2][KF], a_lo[2][KF];
    #pragma unroll
    for (int mf = 0; mf < 2; ++mf) {
        const int eloc = w * 32 + mf * 16 + l15;
        const float* xrow = xin + (size_t)s_src[eloc] * CIN;
        #pragma unroll
        for (int kf = 0; kf < KF; ++kf) {
            if (CIN % 32 == 0) {
                float4 p0 = *(const float4*)(xrow + kf * 32 + lg * 8);
                float4 p1 = *(const float4*)(xrow + kf * 32 + lg * 8 + 4);
                float vv[8] = {p0.x, p0.y, p0.z, p0.w, p1.x, p1.y, p1.z, p1.w};
                #pragma unroll
                for (int j = 0; j < 8; ++j) {
                    unsigned short hb = f2bf(vv[j]);
                    a_hi[mf][kf][j] = (short)hb;
                    a_lo[mf][kf][j] = (short)f2bf(vv[j] - bf2f(hb));
                }
            } else {
                #pragma unroll
                for (int j = 0; j < 8; ++j) {
                    int k = kf * 32 + lg * 8 + j;
                    float v = (k < CIN) ? xrow[k] : 0.f;
                    unsigned short hb = f2bf(v);
                    a_hi[mf][kf][j] = (short)hb;
                    a_lo[mf][kf][j] = (short)f2bf(v - bf2f(hb));
                }
            }
        }
    }

    f32x4 msg[2][4];
    #pragma unroll
    for (int mf = 0; mf < 2; ++mf)
        #pragma unroll
        for (int nf = 0; nf < 4; ++nf) msg[mf][nf] = 0.f;

    // ---- staging helpers ----
    auto stage = [&](int khg, int c, int p) {
        if (khg >= kh1) return;
        const int n_ = tid & 63;
        const int i0 = (tid >> 6) * 8;
        const float* bsrc = (khg < KH) ? (w2 + ((size_t)khg * CIN + c * 32) * COUT)
                                       : (b2 + (size_t)(c * 32) * COUT);
        unsigned short hb[8], lb[8];
        #pragma unroll
        for (int j = 0; j < 8; ++j) {
            float v = 0.f;
            if (c * 32 + i0 + j < CIN) v = bsrc[(size_t)(i0 + j) * COUT + n0 + n_];
            hb[j] = f2bf(v);
            lb[j] = f2bf(v - bf2f(hb[j]));
        }
        *(short4*)&bsh[p][0][n_][i0]     = make_short4((short)hb[0], (short)hb[1], (short)hb[2], (short)hb[3]);
        *(short4*)&bsh[p][0][n_][i0 + 4] = make_short4((short)hb[4], (short)hb[5], (short)hb[6], (short)hb[7]);
        *(short4*)&bsh[p][1][n_][i0]     = make_short4((short)lb[0], (short)lb[1], (short)lb[2], (short)lb[3]);
        *(short4*)&bsh[p][1][n_][i0 + 4] = make_short4((short)lb[4], (short)lb[5], (short)lb[6], (short)lb[7]);
    };
    auto stage_h = [&](int khg) {
        if (tid < BM && khg < kh1 && khg < KH)
            s_h[khg & 1][tid] = hT[(size_t)khg * E + e0 + tid];
    };

    // prologue
    stage(kh0, 0, 0);
    stage_h(kh0);

    for (int khg = kh0; khg < kh1; ++khg) {
        f32x4 T[2][4];
        #pragma unroll
        for (int mf = 0; mf < 2; ++mf)
            #pragma unroll
            for (int nf = 0; nf < 4; ++nf) T[mf][nf] = 0.f;

        #pragma unroll
        for (int c = 0; c < KF; ++c) {
            const int p = c & 1;          // KF even -> parity static across khg
            __syncthreads();
            // stage next chunk into the other buffer
            if (c == KF - 1) { stage(khg + 1, 0, p ^ 1); stage_h(khg + 1); }
            else             { stage(khg, c + 1, p ^ 1); }

            #pragma unroll
            for (int nf = 0; nf < 4; ++nf) {
                const int row = nf * 16 + l15;
                s16x8 Bh = *(const s16x8*)&bsh[p][0][row][lg * 8];
                s16x8 Bl = *(const s16x8*)&bsh[p][1][row][lg * 8];
                #pragma unroll
                for (int mf = 0; mf < 2; ++mf) {
                    T[mf][nf] = __builtin_amdgcn_mfma_f32_16x16x32_bf16(a_hi[mf][c], Bh, T[mf][nf], 0, 0, 0);
                    T[mf][nf] = __builtin_amdgcn_mfma_f32_16x16x32_bf16(a_lo[mf][c], Bh, T[mf][nf], 0, 0, 0);
                    T[mf][nf] = __builtin_amdgcn_mfma_f32_16x16x32_bf16(a_hi[mf][c], Bl, T[mf][nf], 0, 0, 0);
                }
            }
        }

        // msg += h[e,khg] * T (exact fp32 row scale)
        float hv[2][4];
        #pragma unroll
        for (int mf = 0; mf < 2; ++mf)
            #pragma unroll
            for (int r = 0; r < 4; ++r)
                hv[mf][r] = (khg < KH) ? s_h[khg & 1][w * 32 + mf * 16 + lg * 4 + r] : 1.f;
        #pragma unroll
        for (int mf = 0; mf < 2; ++mf)
            #pragma unroll
            for (int nf = 0; nf < 4; ++nf)
                #pragma unroll
                for (int r = 0; r < 4; ++r)
                    msg[mf][nf][r] += hv[mf][r] * T[mf][nf][r];
    }

    // ---- scatter-add epilogue ----
    #pragma unroll
    for (int mf = 0; mf < 2; ++mf)
        #pragma unroll
        for (int r = 0; r < 4; ++r) {
            const int eloc = w * 32 + mf * 16 + lg * 4 + r;
            const int d = s_dst[eloc];
            #pragma unroll
            for (int nf = 0; nf < 4; ++nf)
                atomicAdd(&agg[(size_t)d * COUT + n0 + nf * 16 + l15], msg[mf][nf][r]);
        }
}

// ---------------- node GEMM (fp32): out = elu(x@root + agg + bias) ----------------
template <int CIN, int COUT>
__global__ __launch_bounds__(256)
void node_gemm_kernel(const float* __restrict__ xin,
                      const float* __restrict__ root,
                      const float* __restrict__ agg_in,
                      const float* __restrict__ bias,
                      float* __restrict__ out)
{
    constexpr int BM  = 64;
    constexpr int BN  = 64;
    constexpr int BKI = (CIN % 32 == 0) ? 32 : 16;
    constexpr int CIN_PAD = ((CIN + BKI - 1) / BKI) * BKI;
    constexpr int CPK = CIN_PAD / BKI;
    constexpr int NROWS = BKI / 16;

    __shared__ __align__(16) float xs_t[CIN_PAD][BM];
    __shared__ __align__(16) float btile[BKI][BN];

    const int tid = threadIdx.x;
    const int tx  = tid & 15;
    const int ty  = tid >> 4;
    const int ty4 = ty * 4;
    const int tx4 = tx * 4;
    const int e0  = blockIdx.x * BM;
    const int n0  = blockIdx.y * BN;

    for (int idx = tid; idx < BM * CIN_PAD; idx += 256) {
        int m = idx / CIN_PAD;
        int i = idx - m * CIN_PAD;
        float v = 0.f;
        if (i < CIN) v = xin[(size_t)(e0 + m) * CIN + i];
        xs_t[i][m] = v;
    }

    const int rbase = tid >> 4;
    const int nn    = (tid & 15) * 4;
    float acc[4][4] = {};
    float4 pre[NROWS];

    {
        const float* brow = root + n0;
        #pragma unroll
        for (int rr = 0; rr < NROWS; ++rr) {
            int r = rbase + rr * 16;
            float4 v = {0.f, 0.f, 0.f, 0.f};
            if (r < CIN) v = *(const float4*)(brow + (size_t)r * COUT + nn);
            pre[rr] = v;
        }
    }

    for (int c = 0; c < CPK; ++c) {
        __syncthreads();
        #pragma unroll
        for (int rr = 0; rr < NROWS; ++rr)
            *(float4*)&btile[rbase + rr * 16][nn] = pre[rr];
        __syncthreads();

        if (c + 1 < CPK) {
            int i0n = (c + 1) * BKI;
            const float* brow = root + (size_t)i0n * COUT + n0;
            #pragma unroll
            for (int rr = 0; rr < NROWS; ++rr) {
                int r = rbase + rr * 16;
                float4 v = {0.f, 0.f, 0.f, 0.f};
                if (i0n + r < CIN) v = *(const float4*)(brow + (size_t)r * COUT + nn);
                pre[rr] = v;
            }
        }

        const int i0 = c * BKI;
        #pragma unroll
        for (int ii = 0; ii < BKI; ++ii) {
            float4 xv = *(const float4*)&xs_t[i0 + ii][ty4];
            float4 bv = *(const float4*)&btile[ii][tx4];
            float av[4] = {xv.x, xv.y, xv.z, xv.w};
            float bvv[4] = {bv.x, bv.y, bv.z, bv.w};
            #pragma unroll
            for (int m = 0; m < 4; ++m)
                #pragma unroll
                for (int n = 0; n < 4; ++n)
                    acc[m][n] = fmaf(av[m], bvv[n], acc[m][n]);
        }
    }

    float bs[4];
    #pragma unroll
    for (int n = 0; n < 4; ++n) bs[n] = bias[n0 + tx4 + n];
    #pragma unroll
    for (int m = 0; m < 4; ++m) {
        size_t base = (size_t)(e0 + ty4 + m) * COUT + n0 + tx4;
        #pragma unroll
        for (int n = 0; n < 4; ++n) {
            float v = acc[m][n] + agg_in[base + n] + bs[n];
            out[base + n] = elu_f(v);
        }
    }
}

// ---------------- graph pooling ----------------
__global__ __launch_bounds__(256)
void seg_sum_kernel(const float* __restrict__ hl3, const int* __restrict__ batch,
                    float* __restrict__ gsum, float* __restrict__ gcnt)
{
    const int n = blockIdx.x;
    const int b = batch[n];
    const int o = threadIdx.x;
    atomicAdd(&gsum[(size_t)b * 256 + o], hl3[(size_t)n * 256 + o]);
    if (o == 0) atomicAdd(&gcnt[b], 1.f);
}

// ---------------- readout MLP ----------------
__global__ __launch_bounds__(256)
void readout_kernel(const float* __restrict__ gsum, const float* __restrict__ gcnt,
                    const float* __restrict__ fc1w, const float* __restrict__ fc1b,
                    const float* __restrict__ fc2w, const float* __restrict__ fc2b,
                    const float* __restrict__ fc3w, const float* __restrict__ fc3b,
                    float* __restrict__ outp)
{
    const int g   = blockIdx.x;
    const int tid = threadIdx.x;
    __shared__ float gm[256];
    __shared__ float a1[128];
    __shared__ float a2[64];
    float cnt = fmaxf(gcnt[g], 1.f);
    gm[tid] = gsum[(size_t)g * 256 + tid] / cnt;
    __syncthreads();
    if (tid < 128) {
        float s = fc1b[tid];
        for (int j = 0; j < 256; ++j) s = fmaf(gm[j], fc1w[j * 128 + tid], s);
        a1[tid] = elu_f(s);
    }
    __syncthreads();
    if (tid < 64) {
        float s = fc2b[tid];
        for (int j = 0; j < 128; ++j) s = fmaf(a1[j], fc2w[j * 64 + tid], s);
        a2[tid] = elu_f(s);
    }
    __syncthreads();
    if (tid == 0) {
        float s = fc3b[0];
        for (int j = 0; j < 64; ++j) s = fmaf(a2[j], fc3w[j], s);
        outp[g] = s;
    }
}

extern "C" void kernel_launch(void* const* d_in, const int* in_sizes, int n_in,
                              void* d_out, int out_size, void* d_ws, size_t ws_size,
                              hipStream_t stream)
{
    const float* x      = (const float*)d_in[0];
    const int*   ei     = (const int*)  d_in[1];
    const float* ea     = (const float*)d_in[2];
    const int*   batch  = (const int*)  d_in[3];
    const float* nn1_w1 = (const float*)d_in[4];
    const float* nn1_b1 = (const float*)d_in[5];
    const float* nn1_w2 = (const float*)d_in[6];
    const float* nn1_b2 = (const float*)d_in[7];
    const float* root1  = (const float*)d_in[8];
    const float* bias1  = (const float*)d_in[9];
    const float* nn2_w1 = (const float*)d_in[10];
    const float* nn2_b1 = (const float*)d_in[11];
    const float* nn2_w2 = (const float*)d_in[12];
    const float* nn2_b2 = (const float*)d_in[13];
    const float* root2  = (const float*)d_in[14];
    const float* bias2  = (const float*)d_in[15];
    const float* nn3_w1 = (const float*)d_in[16];
    const float* nn3_b1 = (const float*)d_in[17];
    const float* nn3_w2 = (const float*)d_in[18];
    const float* nn3_b2 = (const float*)d_in[19];
    const float* root3  = (const float*)d_in[20];
    const float* bias3  = (const float*)d_in[21];
    const float* fc1_w  = (const float*)d_in[22];
    const float* fc1_b  = (const float*)d_in[23];
    const float* fc2_w  = (const float*)d_in[24];
    const float* fc2_b  = (const float*)d_in[25];
    const float* fc3_w  = (const float*)d_in[26];
    const float* fc3_b  = (const float*)d_in[27];

    const int E = in_sizes[2] / 5;    // 4096
    const int N = in_sizes[0] / 37;   // 4096
    const int* srcp = ei;
    const int* dstp = ei + E;

    float* ws   = (float*)d_ws;
    float* h1T  = ws;                              // [512, E]
    float* h2T  = h1T + (size_t)512 * E;           // [128, E]
    float* h3T  = h2T + (size_t)128 * E;           // [128, E]
    float* hl1  = h3T + (size_t)128 * E;           // [N,128]
    float* hl2  = hl1 + (size_t)N * 128;           // [N,256]
    float* hl3  = hl2 + (size_t)N * 256;           // [N,256]
    float* agg1 = hl3 + (size_t)N * 256;           // zeroed region starts here
    float* agg2 = agg1 + (size_t)N * 128;
    float* agg3 = agg2 + (size_t)N * 256;
    float* gsum = agg3 + (size_t)N * 256;          // [128,256]
    float* gcnt = gsum + (size_t)128 * 256;        // [128]

    const size_t zero_floats = (size_t)N * 128 + (size_t)N * 256 + (size_t)N * 256
                             + (size_t)128 * 256 + 128;
    hipMemsetAsync(agg1, 0, zero_floats * sizeof(float), stream);

    edge_mlp_kernel<<<E, 256, 0, stream>>>(ea, nn1_w1, nn1_b1, h1T,
                                           nn2_w1, nn2_b1, h2T,
                                           nn3_w1, nn3_b1, h3T, E);

    const int MB = E / 128;   // 32

    // layer 1: cin=37 -> cout=128, edge hidden 512; kh-split 8 x 65 >= 513
    msg_mfma_kernel<512, 37, 128><<<dim3(MB, 2, 8), 256, 0, stream>>>(
        x, h1T, nn1_w2, nn1_b2, srcp, dstp, agg1, E, 65);
    node_gemm_kernel<37, 128><<<dim3(N / 64, 2), 256, 0, stream>>>(
        x, root1, agg1, bias1, hl1);

    // layer 2: cin=128 -> cout=256, edge hidden 128; kh-split 4 x 33 >= 129
    msg_mfma_kernel<128, 128, 256><<<dim3(MB, 4, 4), 256, 0, stream>>>(
        hl1, h2T, nn2_w2, nn2_b2, srcp, dstp, agg2, E, 33);
    node_gemm_kernel<128, 256><<<dim3(N / 64, 4), 256, 0, stream>>>(
        hl1, root2, agg2, bias2, hl2);

    // layer 3: cin=256 -> cout=256, edge hidden 128
    msg_mfma_kernel<128, 256, 256><<<dim3(MB, 4, 4), 256, 0, stream>>>(
        hl2, h3T, nn3_w2, nn3_b2, srcp, dstp, agg3, E, 33);
    node_gemm_kernel<256, 256><<<dim3(N / 64, 4), 256, 0, stream>>>(
        hl2, root3, agg3, bias3, hl3);

    seg_sum_kernel<<<N, 256, 0, stream>>>(hl3, batch, gsum, gcnt);
    readout_kernel<<<128, 256, 0, stream>>>(gsum, gcnt, fc1_w, fc1_b,
                                            fc2_w, fc2_b, fc3_w, fc3_b,
                                            (float*)d_out);
}

// Round 3
// 534.713 us; speedup vs baseline: 8.9701x; 1.2436x over previous
//
#include <hip/hip_runtime.h>
#include <cstdint>
#include <cstddef>

typedef float f32x4 __attribute__((ext_vector_type(4)));
typedef _Float16 f16x8 __attribute__((ext_vector_type(8)));

__device__ __forceinline__ float elu_f(float x) { return x > 0.f ? x : expm1f(x); }

// ---------------- edge MLP: hT_l[c][e] = relu(edge_attr @ w1_l + b1_l), coalesced ----
__global__ __launch_bounds__(256)
void edge_mlp_kernel(const float* __restrict__ ea,
                     const float* __restrict__ w1a, const float* __restrict__ b1a, float* __restrict__ h1T,
                     const float* __restrict__ w1b, const float* __restrict__ b1b, float* __restrict__ h2T,
                     const float* __restrict__ w1c, const float* __restrict__ b1c, float* __restrict__ h3T,
                     int E)
{
    const int e0  = blockIdx.x * 64;
    const int tid = threadIdx.x;
    const int el  = tid & 63;
    const int cg  = tid >> 6;          // 0..3
    __shared__ float a[64][5];
    for (int i = tid; i < 320; i += 256) a[i / 5][i % 5] = ea[e0 * 5 + i];
    __syncthreads();
    float av[5];
    #pragma unroll
    for (int j = 0; j < 5; ++j) av[j] = a[el][j];

    #pragma unroll 4
    for (int t = 0; t < 128; ++t) {
        const int ch = t * 4 + cg;
        float s = b1a[ch];
        #pragma unroll
        for (int j = 0; j < 5; ++j) s = fmaf(av[j], w1a[j * 512 + ch], s);
        h1T[(size_t)ch * E + e0 + el] = fmaxf(s, 0.f);
    }
    #pragma unroll 4
    for (int t = 0; t < 32; ++t) {
        const int ch = t * 4 + cg;
        float s = b1b[ch];
        float u = b1c[ch];
        #pragma unroll
        for (int j = 0; j < 5; ++j) {
            s = fmaf(av[j], w1b[j * 128 + ch], s);
            u = fmaf(av[j], w1c[j * 128 + ch], u);
        }
        h2T[(size_t)ch * E + e0 + el] = fmaxf(s, 0.f);
        h3T[(size_t)ch * E + e0 + el] = fmaxf(u, 0.f);
    }
}

// ---------------- pack w2 (+b2 as last slab) into fp16 [slab][COUT][32] ----------------
template <int CIN, int COUT, int KF>
__global__ __launch_bounds__(256)
void pack_w2_kernel(const float* __restrict__ w2, const float* __restrict__ b2,
                    _Float16* __restrict__ w2h, int KH)
{
    __shared__ _Float16 tile[32][COUT + 2];
    const int bid = blockIdx.x;
    const int kh  = bid / KF;
    const int c   = bid - kh * KF;
    const int tid = threadIdx.x;
    const int CP  = 32 * COUT;
    for (int i = tid; i < CP; i += 256) {
        int kk = i / COUT, n = i - kk * COUT;
        int kg = c * 32 + kk;
        float v = 0.f;
        if (kg < CIN) v = (kh < KH) ? w2[((size_t)kh * CIN + kg) * COUT + n]
                                    : b2[(size_t)kg * COUT + n];
        tile[kk][n] = (_Float16)v;
    }
    __syncthreads();
    _Float16* outp = w2h + (size_t)bid * CP;
    for (int i = tid; i < CP; i += 256) {
        int n = i >> 5, kk = i & 31;
        outp[i] = tile[kk][n];
    }
}

// ---------------- MFMA message kernel (fp16 single product) ----------------
// agg[dst[e]][n0+n] += sum_kh h[e,kh] * (X @ W2[kh])[e,n]   (+ X @ b2 at kh==KH)
template <int KH, int CIN, int COUT>
__global__ __launch_bounds__(256, 2)
void msg_mfma_kernel(const float* __restrict__ xin,     // [*, CIN] fp32 (gathered via src)
                     const float* __restrict__ hT,      // [KH, E] fp32
                     const _Float16* __restrict__ w2h,  // [(KH+1)*KF][COUT][32]
                     const int* __restrict__ src,
                     const int* __restrict__ dst,
                     float* __restrict__ agg,           // [N, COUT]
                     int E, int khg_per)
{
    constexpr int BM = 128;
    constexpr int KF = (CIN + 31) / 32;

    __shared__ __align__(16) _Float16 bsh[2][KF][64][32];
    __shared__ float s_h[2][BM];
    __shared__ int   s_src[BM];
    __shared__ int   s_dst[BM];

    const int tid  = threadIdx.x;
    const int lane = tid & 63;
    const int w    = tid >> 6;        // wave 0..3 -> rows w*32..w*32+31
    const int l15  = lane & 15;
    const int lg   = lane >> 4;       // 0..3
    const int e0   = blockIdx.x * BM;
    const int n0   = blockIdx.y * 64;
    const int kh0  = blockIdx.z * khg_per;
    const int kh1  = min(kh0 + khg_per, KH + 1);

    if (tid < BM) { s_src[tid] = src[e0 + tid]; s_dst[tid] = dst[e0 + tid]; }
    __syncthreads();

    // ---- gather A (X rows) into fp16 register fragments ----
    f16x8 a_[2][KF];
    #pragma unroll
    for (int mf = 0; mf < 2; ++mf) {
        const int eloc = w * 32 + mf * 16 + l15;
        const float* xrow = xin + (size_t)s_src[eloc] * CIN;
        #pragma unroll
        for (int kf = 0; kf < KF; ++kf) {
            if (CIN % 32 == 0) {
                float4 p0 = *(const float4*)(xrow + kf * 32 + lg * 8);
                float4 p1 = *(const float4*)(xrow + kf * 32 + lg * 8 + 4);
                a_[mf][kf][0] = (_Float16)p0.x; a_[mf][kf][1] = (_Float16)p0.y;
                a_[mf][kf][2] = (_Float16)p0.z; a_[mf][kf][3] = (_Float16)p0.w;
                a_[mf][kf][4] = (_Float16)p1.x; a_[mf][kf][5] = (_Float16)p1.y;
                a_[mf][kf][6] = (_Float16)p1.z; a_[mf][kf][7] = (_Float16)p1.w;
            } else {
                #pragma unroll
                for (int j = 0; j < 8; ++j) {
                    int k = kf * 32 + lg * 8 + j;
                    float v = (k < CIN) ? xrow[k] : 0.f;
                    a_[mf][kf][j] = (_Float16)v;
                }
            }
        }
    }

    f32x4 msg[2][4];
    #pragma unroll
    for (int mf = 0; mf < 2; ++mf)
        #pragma unroll
        for (int nf = 0; nf < 4; ++nf) msg[mf][nf] = 0.f;

    const int nrow = tid >> 2;        // 0..63
    const int kq   = tid & 3;         // 16B quarter

    // ---- prologue: stage slab kh0 into buffer 0 ----
    int p = 0;
    {
        uint4 st0[KF];
        const _Float16* sb = w2h + (((size_t)kh0 * KF) * COUT + n0 + nrow) * 32 + kq * 8;
        #pragma unroll
        for (int c = 0; c < KF; ++c)
            st0[c] = *(const uint4*)(sb + (size_t)c * COUT * 32);
        float h0 = 1.f;
        const bool hv0 = (tid < BM) && (kh0 < KH);
        if (hv0) h0 = hT[(size_t)kh0 * E + e0 + tid];
        #pragma unroll
        for (int c = 0; c < KF; ++c)
            *(uint4*)&bsh[0][c][nrow][kq * 8] = st0[c];
        if (hv0) s_h[kh0 & 1][tid] = h0;
    }

    for (int khg = kh0; khg < kh1; ++khg) {
        __syncthreads();                      // slab p + s_h ready; p^1 free

        // issue next-slab loads (in flight across compute)
        const bool have = (khg + 1 < kh1);
        uint4 stg[KF];
        if (have) {
            const _Float16* sb = w2h + (((size_t)(khg + 1) * KF) * COUT + n0 + nrow) * 32 + kq * 8;
            #pragma unroll
            for (int c = 0; c < KF; ++c)
                stg[c] = *(const uint4*)(sb + (size_t)c * COUT * 32);
        }
        float hnext = 1.f;
        const bool hv_have = (tid < BM) && (khg + 1 < kh1) && (khg + 1 < KH);
        if (hv_have) hnext = hT[(size_t)(khg + 1) * E + e0 + tid];

        // compute slab p: KF chunks x 4 nf x 2 mf MFMA
        f32x4 T[2][4];
        #pragma unroll
        for (int mf = 0; mf < 2; ++mf)
            #pragma unroll
            for (int nf = 0; nf < 4; ++nf) T[mf][nf] = 0.f;

        #pragma unroll
        for (int c = 0; c < KF; ++c) {
            #pragma unroll
            for (int nf = 0; nf < 4; ++nf) {
                f16x8 B = *(const f16x8*)&bsh[p][c][nf * 16 + l15][lg * 8];
                T[0][nf] = __builtin_amdgcn_mfma_f32_16x16x32_f16(a_[0][c], B, T[0][nf], 0, 0, 0);
                T[1][nf] = __builtin_amdgcn_mfma_f32_16x16x32_f16(a_[1][c], B, T[1][nf], 0, 0, 0);
            }
        }

        // msg += h[e,khg] * T (fp32 row scale)
        const float* hrow = s_h[khg & 1];
        #pragma unroll
        for (int mf = 0; mf < 2; ++mf)
            #pragma unroll
            for (int r = 0; r < 4; ++r) {
                float hv = (khg < KH) ? hrow[w * 32 + mf * 16 + lg * 4 + r] : 1.f;
                #pragma unroll
                for (int nf = 0; nf < 4; ++nf)
                    msg[mf][nf][r] = fmaf(hv, T[mf][nf][r], msg[mf][nf][r]);
            }

        // late write: next slab into p^1 (vmcnt drain hidden under compute)
        if (have) {
            #pragma unroll
            for (int c = 0; c < KF; ++c)
                *(uint4*)&bsh[p ^ 1][c][nrow][kq * 8] = stg[c];
            if (hv_have) s_h[(khg + 1) & 1][tid] = hnext;
        }
        p ^= 1;
    }

    // ---- scatter-add epilogue ----
    #pragma unroll
    for (int mf = 0; mf < 2; ++mf)
        #pragma unroll
        for (int r = 0; r < 4; ++r) {
            const int eloc = w * 32 + mf * 16 + lg * 4 + r;
            const int d = s_dst[eloc];
            #pragma unroll
            for (int nf = 0; nf < 4; ++nf)
                atomicAdd(&agg[(size_t)d * COUT + n0 + nf * 16 + l15], msg[mf][nf][r]);
        }
}

// ---------------- node GEMM (fp32): out = elu(x@root + agg + bias) ----------------
template <int CIN, int COUT>
__global__ __launch_bounds__(256)
void node_gemm_kernel(const float* __restrict__ xin,
                      const float* __restrict__ root,
                      const float* __restrict__ agg_in,
                      const float* __restrict__ bias,
                      float* __restrict__ out)
{
    constexpr int BM  = 64;
    constexpr int BN  = 64;
    constexpr int BKI = (CIN % 32 == 0) ? 32 : 16;
    constexpr int CIN_PAD = ((CIN + BKI - 1) / BKI) * BKI;
    constexpr int CPK = CIN_PAD / BKI;
    constexpr int NROWS = BKI / 16;

    __shared__ __align__(16) float xs_t[CIN_PAD][BM];
    __shared__ __align__(16) float btile[BKI][BN];

    const int tid = threadIdx.x;
    const int tx  = tid & 15;
    const int ty  = tid >> 4;
    const int ty4 = ty * 4;
    const int tx4 = tx * 4;
    const int e0  = blockIdx.x * BM;
    const int n0  = blockIdx.y * BN;

    for (int idx = tid; idx < BM * CIN_PAD; idx += 256) {
        int m = idx / CIN_PAD;
        int i = idx - m * CIN_PAD;
        float v = 0.f;
        if (i < CIN) v = xin[(size_t)(e0 + m) * CIN + i];
        xs_t[i][m] = v;
    }

    const int rbase = tid >> 4;
    const int nn    = (tid & 15) * 4;
    float acc[4][4] = {};
    float4 pre[NROWS];

    {
        const float* brow = root + n0;
        #pragma unroll
        for (int rr = 0; rr < NROWS; ++rr) {
            int r = rbase + rr * 16;
            float4 v = {0.f, 0.f, 0.f, 0.f};
            if (r < CIN) v = *(const float4*)(brow + (size_t)r * COUT + nn);
            pre[rr] = v;
        }
    }

    for (int c = 0; c < CPK; ++c) {
        __syncthreads();
        #pragma unroll
        for (int rr = 0; rr < NROWS; ++rr)
            *(float4*)&btile[rbase + rr * 16][nn] = pre[rr];
        __syncthreads();

        if (c + 1 < CPK) {
            int i0n = (c + 1) * BKI;
            const float* brow = root + (size_t)i0n * COUT + n0;
            #pragma unroll
            for (int rr = 0; rr < NROWS; ++rr) {
                int r = rbase + rr * 16;
                float4 v = {0.f, 0.f, 0.f, 0.f};
                if (i0n + r < CIN) v = *(const float4*)(brow + (size_t)r * COUT + nn);
                pre[rr] = v;
            }
        }

        const int i0 = c * BKI;
        #pragma unroll
        for (int ii = 0; ii < BKI; ++ii) {
            float4 xv = *(const float4*)&xs_t[i0 + ii][ty4];
            float4 bv = *(const float4*)&btile[ii][tx4];
            float av[4] = {xv.x, xv.y, xv.z, xv.w};
            float bvv[4] = {bv.x, bv.y, bv.z, bv.w};
            #pragma unroll
            for (int m = 0; m < 4; ++m)
                #pragma unroll
                for (int n = 0; n < 4; ++n)
                    acc[m][n] = fmaf(av[m], bvv[n], acc[m][n]);
        }
    }

    float bs[4];
    #pragma unroll
    for (int n = 0; n < 4; ++n) bs[n] = bias[n0 + tx4 + n];
    #pragma unroll
    for (int m = 0; m < 4; ++m) {
        size_t base = (size_t)(e0 + ty4 + m) * COUT + n0 + tx4;
        #pragma unroll
        for (int n = 0; n < 4; ++n) {
            float v = acc[m][n] + agg_in[base + n] + bs[n];
            out[base + n] = elu_f(v);
        }
    }
}

// ---------------- graph pooling ----------------
__global__ __launch_bounds__(256)
void seg_sum_kernel(const float* __restrict__ hl3, const int* __restrict__ batch,
                    float* __restrict__ gsum, float* __restrict__ gcnt)
{
    const int n = blockIdx.x;
    const int b = batch[n];
    const int o = threadIdx.x;
    atomicAdd(&gsum[(size_t)b * 256 + o], hl3[(size_t)n * 256 + o]);
    if (o == 0) atomicAdd(&gcnt[b], 1.f);
}

// ---------------- readout MLP ----------------
__global__ __launch_bounds__(256)
void readout_kernel(const float* __restrict__ gsum, const float* __restrict__ gcnt,
                    const float* __restrict__ fc1w, const float* __restrict__ fc1b,
                    const float* __restrict__ fc2w, const float* __restrict__ fc2b,
                    const float* __restrict__ fc3w, const float* __restrict__ fc3b,
                    float* __restrict__ outp)
{
    const int g   = blockIdx.x;
    const int tid = threadIdx.x;
    __shared__ float gm[256];
    __shared__ float a1[128];
    __shared__ float a2[64];
    float cnt = fmaxf(gcnt[g], 1.f);
    gm[tid] = gsum[(size_t)g * 256 + tid] / cnt;
    __syncthreads();
    if (tid < 128) {
        float s = fc1b[tid];
        for (int j = 0; j < 256; ++j) s = fmaf(gm[j], fc1w[j * 128 + tid], s);
        a1[tid] = elu_f(s);
    }
    __syncthreads();
    if (tid < 64) {
        float s = fc2b[tid];
        for (int j = 0; j < 128; ++j) s = fmaf(a1[j], fc2w[j * 64 + tid], s);
        a2[tid] = elu_f(s);
    }
    __syncthreads();
    if (tid == 0) {
        float s = fc3b[0];
        for (int j = 0; j < 64; ++j) s = fmaf(a2[j], fc3w[j], s);
        outp[g] = s;
    }
}

extern "C" void kernel_launch(void* const* d_in, const int* in_sizes, int n_in,
                              void* d_out, int out_size, void* d_ws, size_t ws_size,
                              hipStream_t stream)
{
    const float* x      = (const float*)d_in[0];
    const int*   ei     = (const int*)  d_in[1];
    const float* ea     = (const float*)d_in[2];
    const int*   batch  = (const int*)  d_in[3];
    const float* nn1_w1 = (const float*)d_in[4];
    const float* nn1_b1 = (const float*)d_in[5];
    const float* nn1_w2 = (const float*)d_in[6];
    const float* nn1_b2 = (const float*)d_in[7];
    const float* root1  = (const float*)d_in[8];
    const float* bias1  = (const float*)d_in[9];
    const float* nn2_w1 = (const float*)d_in[10];
    const float* nn2_b1 = (const float*)d_in[11];
    const float* nn2_w2 = (const float*)d_in[12];
    const float* nn2_b2 = (const float*)d_in[13];
    const float* root2  = (const float*)d_in[14];
    const float* bias2  = (const float*)d_in[15];
    const float* nn3_w1 = (const float*)d_in[16];
    const float* nn3_b1 = (const float*)d_in[17];
    const float* nn3_w2 = (const float*)d_in[18];
    const float* nn3_b2 = (const float*)d_in[19];
    const float* root3  = (const float*)d_in[20];
    const float* bias3  = (const float*)d_in[21];
    const float* fc1_w  = (const float*)d_in[22];
    const float* fc1_b  = (const float*)d_in[23];
    const float* fc2_w  = (const float*)d_in[24];
    const float* fc2_b  = (const float*)d_in[25];
    const float* fc3_w  = (const float*)d_in[26];
    const float* fc3_b  = (const float*)d_in[27];

    const int E = in_sizes[2] / 5;    // 4096
    const int N = in_sizes[0] / 37;   // 4096
    const int* srcp = ei;
    const int* dstp = ei + E;

    // ---- workspace layout ----
    const size_t W1H = (size_t)513 * 2 * 128 * 32;   // 4,202,496 halfs
    const size_t W2H = (size_t)129 * 4 * 256 * 32;   // 4,227,072
    const size_t W3H = (size_t)129 * 8 * 256 * 32;   // 8,454,144
    _Float16* w2h1 = (_Float16*)d_ws;
    _Float16* w2h2 = w2h1 + W1H;
    _Float16* w2h3 = w2h2 + W2H;
    float* fbase = (float*)(w2h3 + W3H);

    float* h1T  = fbase;                           // [512, E]
    float* h2T  = h1T + (size_t)512 * E;           // [128, E]
    float* h3T  = h2T + (size_t)128 * E;           // [128, E]
    float* hl1  = h3T + (size_t)128 * E;           // [N,128]
    float* hl2  = hl1 + (size_t)N * 128;           // [N,256]
    float* hl3  = hl2 + (size_t)N * 256;           // [N,256]
    float* agg1 = hl3 + (size_t)N * 256;           // zeroed region starts here
    float* agg2 = agg1 + (size_t)N * 128;
    float* agg3 = agg2 + (size_t)N * 256;
    float* gsum = agg3 + (size_t)N * 256;          // [128,256]
    float* gcnt = gsum + (size_t)128 * 256;        // [128]

    const size_t zero_floats = (size_t)N * 128 + (size_t)N * 256 + (size_t)N * 256
                             + (size_t)128 * 256 + 128;
    hipMemsetAsync(agg1, 0, zero_floats * sizeof(float), stream);

    edge_mlp_kernel<<<E / 64, 256, 0, stream>>>(ea, nn1_w1, nn1_b1, h1T,
                                                nn2_w1, nn2_b1, h2T,
                                                nn3_w1, nn3_b1, h3T, E);

    pack_w2_kernel<37, 128, 2><<<513 * 2, 256, 0, stream>>>(nn1_w2, nn1_b2, w2h1, 512);
    pack_w2_kernel<128, 256, 4><<<129 * 4, 256, 0, stream>>>(nn2_w2, nn2_b2, w2h2, 128);
    pack_w2_kernel<256, 256, 8><<<129 * 8, 256, 0, stream>>>(nn3_w2, nn3_b2, w2h3, 128);

    const int MB = E / 128;   // 32

    // layer 1: cin=37 -> cout=128, edge hidden 512; kh-split 8 x 65 >= 513
    msg_mfma_kernel<512, 37, 128><<<dim3(MB, 2, 8), 256, 0, stream>>>(
        x, h1T, w2h1, srcp, dstp, agg1, E, 65);
    node_gemm_kernel<37, 128><<<dim3(N / 64, 2), 256, 0, stream>>>(
        x, root1, agg1, bias1, hl1);

    // layer 2: cin=128 -> cout=256, edge hidden 128; kh-split 4 x 33 >= 129
    msg_mfma_kernel<128, 128, 256><<<dim3(MB, 4, 4), 256, 0, stream>>>(
        hl1, h2T, w2h2, srcp, dstp, agg2, E, 33);
    node_gemm_kernel<128, 256><<<dim3(N / 64, 4), 256, 0, stream>>>(
        hl1, root2, agg2, bias2, hl2);

    // layer 3: cin=256 -> cout=256, edge hidden 128; kh-split 4 x 33 >= 129
    msg_mfma_kernel<128, 256, 256><<<dim3(MB, 4, 4), 256, 0, stream>>>(
        hl2, h3T, w2h3, srcp, dstp, agg3, E, 33);
    node_gemm_kernel<256, 256><<<dim3(N / 64, 4), 256, 0, stream>>>(
        hl2, root3, agg3, bias3, hl3);

    seg_sum_kernel<<<N, 256, 0, stream>>>(hl3, batch, gsum, gcnt);
    readout_kernel<<<128, 256, 0, stream>>>(gsum, gcnt, fc1_w, fc1_b,
                                            fc2_w, fc2_b, fc3_w, fc3_b,
                                            (float*)d_out);
}